// Round 6
// baseline (362.338 us; speedup 1.0000x reference)
//
#include <hip/hip_runtime.h>
#include <stdint.h>

#define BATCH 32
#define SEQ   1024
#define DIM   768
#define NQKV  2304   // 3*DIM

typedef unsigned short u16;
typedef __attribute__((ext_vector_type(8))) short short8;   // 8 x bf16 (4 VGPRs)
typedef __attribute__((ext_vector_type(4))) float f32x4;
typedef __attribute__((ext_vector_type(4))) unsigned short us4;

// fp32 -> bf16 round-to-nearest-even (finite inputs)
static __device__ __forceinline__ u16 f2bf(float f) {
  uint32_t u = __float_as_uint(f);
  uint32_t r = (u + 0x7fffu + ((u >> 16) & 1u)) >> 16;
  return (u16)r;
}

static __device__ __forceinline__ void gload_lds16(const void* g, void* l) {
  __builtin_amdgcn_global_load_lds(
      (const __attribute__((address_space(1))) unsigned int*)g,
      (__attribute__((address_space(3))) unsigned int*)l, 16, 0, 0);
}

// ===========================================================================
// 128x128 bt-GEMM core: ring-2 LDS (32KB total -> 4 blocks/CU with VGPR<=128),
// 4 waves (2M x 2N), wave tile 64x64, BK=32, 16x16x32 bf16 MFMA.
// Per K-tile: issue next tile's global_load_lds FIRST (so the end-of-tile
// __syncthreads vmcnt-drain is already satisfied), then 8 swizzled
// ds_read_b128 frags, 16 MFMA, __syncthreads. Cross-block overlap on the CU
// (4 independent blocks) hides staging latency and the barrier drain.
// ===========================================================================
static __device__ __forceinline__ void gemm128_core(
    const u16* __restrict__ Ab, int lda,
    const u16* __restrict__ Bb, int ldb,
    int KT, char* smemA, char* smemB, f32x4 (&acc)[4][4])
{
  const int tid  = threadIdx.x;
  const int wid  = tid >> 6;
  const int lane = tid & 63;
  const int wrow = (wid >> 1) * 64;
  const int wcol = (wid & 1) * 64;

  #pragma unroll
  for (int m = 0; m < 4; ++m)
    #pragma unroll
    for (int n = 0; n < 4; ++n)
      acc[m][n] = (f32x4){0.f, 0.f, 0.f, 0.f};

  // stage one half-tile (64 rows x 32 k). LDS dest linear; global source
  // inverse-swizzled (involution on byte bits 4-5 keyed by row>>1) so
  // swizzled reads see correct data (rule #21).
  auto stage = [&](const u16* gb, int ld, char* base, int buf, int half, int kt) {
    const int doff = tid << 4;                          // 0..4095
    const int loff = doff ^ (((doff >> 7) & 3) << 4);   // involution
    const int row  = half * 64 + (loff >> 6);           // 0..127
    const int colb = loff & 63;
    const char* src = (const char*)gb + ((size_t)row * ld + (size_t)kt * 32) * 2 + colb;
    char* dst = base + buf * 8192 + half * 4096 + (wid << 10);  // wave-uniform
    gload_lds16(src, dst);
  };
  auto stage_tile = [&](int kt, int buf) {
    stage(Ab, lda, smemA, buf, 0, kt); stage(Ab, lda, smemA, buf, 1, kt);
    stage(Bb, ldb, smemB, buf, 0, kt); stage(Bb, ldb, smemB, buf, 1, kt);
  };

  const int lrow = lane & 15;
  const int c0   = lane >> 4;

  stage_tile(0, 0);
  __syncthreads();

  for (int T = 0; T < KT; ++T) {
    const int buf = T & 1;
    if (T + 1 < KT) stage_tile(T + 1, buf ^ 1);   // issue early: hidden by MFMAs
    const char* ab = smemA + buf * 8192;
    const char* bb = smemB + buf * 8192;
    short8 af[4], bf[4];
    #pragma unroll
    for (int n = 0; n < 4; ++n) {
      const int row = wcol + n * 16 + lrow;
      const int c = c0 ^ ((row >> 1) & 3);
      bf[n] = *(const short8*)(bb + row * 64 + c * 16);
    }
    #pragma unroll
    for (int m = 0; m < 4; ++m) {
      const int row = wrow + m * 16 + lrow;
      const int c = c0 ^ ((row >> 1) & 3);
      af[m] = *(const short8*)(ab + row * 64 + c * 16);
    }
    __builtin_amdgcn_s_setprio(1);
    #pragma unroll
    for (int m = 0; m < 4; ++m)
      #pragma unroll
      for (int n = 0; n < 4; ++n)
        acc[m][n] = __builtin_amdgcn_mfma_f32_16x16x32_bf16(af[m], bf[n], acc[m][n], 0, 0, 0);
    __builtin_amdgcn_s_setprio(0);
    __syncthreads();   // drains vmcnt(0) (next tile landed) + lgkm; WAR-safe
  }
}

// ===========================================================================
// qkv = x @ W + b with decay folded; v written transposed to vT directly.
// 128x128 tiles: grid 256 x 18. nt 0-5 = q, 6-11 = k, 12-17 = v.
// ===========================================================================
__global__ __launch_bounds__(256, 4)
void qkv_gemm_kernel(const u16* __restrict__ Xb, const u16* __restrict__ Wt,
                     const float* __restrict__ bias, u16* __restrict__ qkv,
                     u16* __restrict__ vT) {
  extern __shared__ char smem[];     // 32768
  f32x4 acc[4][4];

  const int bid = blockIdx.x;                      // 4608 blocks, %8==0
  const int swz = (bid & 7) * 576 + (bid >> 3);    // bijective XCD swizzle
  const int mt = swz / 18;                         // 0..255
  const int nt = swz % 18;                         // 0..17

  gemm128_core(Xb + (size_t)mt * 128 * DIM, DIM,
               Wt + (size_t)nt * 128 * DIM, DIM, DIM / 32,
               smem, smem + 16384, acc);

  const int tid = threadIdx.x, wid = tid >> 6, lane = tid & 63;
  const int wrow = (wid >> 1) * 64, wcol = (wid & 1) * 64;
  const int lr = (lane >> 4) * 4, lc = lane & 15;
  const float L2A = -0.014499570f;     // log2(0.99)
  const float ISD = 0.03608439182f;    // 1/sqrt(768)
  const int seg = nt / 6;              // uniform per block
  float bv[4];
  #pragma unroll
  for (int n = 0; n < 4; ++n)
    bv[n] = bias[nt * 128 + wcol + n * 16 + lc];

  if (seg < 2) {
    #pragma unroll
    for (int m = 0; m < 4; ++m) {
      const int grow0 = mt * 128 + wrow + m * 16 + lr;
      #pragma unroll
      for (int j = 0; j < 4; ++j) {
        const int s = (grow0 + j) & (SEQ - 1);
        const float scale = (seg == 0) ? exp2f((float)s * L2A) * ISD
                                       : exp2f(-(float)s * L2A);
        #pragma unroll
        for (int n = 0; n < 4; ++n) {
          const int gcol = nt * 128 + wcol + n * 16 + lc;
          qkv[(size_t)(grow0 + j) * NQKV + gcol] = f2bf((acc[m][n][j] + bv[n]) * scale);
        }
      }
    }
  } else {
    // v block: write transposed into vT[b][d][t]; j = consecutive t -> us4
    #pragma unroll
    for (int m = 0; m < 4; ++m) {
      const int grow0 = mt * 128 + wrow + m * 16 + lr;
      const int b  = grow0 >> 10;
      const int t0 = grow0 & (SEQ - 1);
      #pragma unroll
      for (int n = 0; n < 4; ++n) {
        const int d = (nt - 12) * 128 + wcol + n * 16 + lc;
        us4 val;
        #pragma unroll
        for (int j = 0; j < 4; ++j) val[j] = f2bf(acc[m][n][j] + bv[n]);
        *(us4*)(vT + ((size_t)b * DIM + d) * SEQ + t0) = val;
      }
    }
  }
}

// ---------------------------------------------------------------------------
// x fp32 -> bf16
__global__ __launch_bounds__(256)
void cvt_x_kernel(const float* __restrict__ X, u16* __restrict__ Xb) {
  const size_t i = ((size_t)blockIdx.x * 256 + threadIdx.x) * 8;
  f32x4 a = *(const f32x4*)(X + i);
  f32x4 b = *(const f32x4*)(X + i + 4);
  short8 r;
  #pragma unroll
  for (int j = 0; j < 4; ++j) { r[j] = (short)f2bf(a[j]); r[j + 4] = (short)f2bf(b[j]); }
  *(short8*)(Xb + i) = r;
}

// W [768][2304] fp32 -> Wt [2304][768] bf16
__global__ void wt_kernel(const float* __restrict__ W, u16* __restrict__ Wt) {
  __shared__ u16 t[32][33];
  const int n0 = blockIdx.x * 32, k0 = blockIdx.y * 32;
  const int tx = threadIdx.x, ty = threadIdx.y;
  #pragma unroll
  for (int r = 0; r < 4; ++r)
    t[ty + r * 8][tx] = f2bf(W[(size_t)(k0 + ty + r * 8) * NQKV + n0 + tx]);
  __syncthreads();
  #pragma unroll
  for (int r = 0; r < 4; ++r)
    Wt[(size_t)(n0 + ty + r * 8) * DIM + k0 + tx] = t[tx][ty + r * 8];
}

// S = q~ @ k~^T per batch, lower-triangular tiles only; strict-upper zeroed
__global__ __launch_bounds__(256, 4)
void qk_gemm_kernel(const u16* __restrict__ qkv, u16* __restrict__ S) {
  extern __shared__ char smem[];      // 32768
  f32x4 acc[4][4];
  const int b = blockIdx.y;
  const int p = blockIdx.x;           // 0..35 triangular pair
  int it = 0;
  while ((it + 1) * (it + 2) / 2 <= p) ++it;
  const int jt = p - it * (it + 1) / 2;
  const u16* Ab = qkv + (size_t)(b * SEQ + it * 128) * NQKV;        // q rows
  const u16* Bb = qkv + (size_t)(b * SEQ + jt * 128) * NQKV + DIM;  // k rows
  gemm128_core(Ab, NQKV, Bb, NQKV, DIM / 32, smem, smem + 16384, acc);

  u16* Sb = S + (size_t)b * SEQ * SEQ;
  const int tid = threadIdx.x, wid = tid >> 6, lane = tid & 63;
  const int wrow = (wid >> 1) * 64, wcol = (wid & 1) * 64;
  const int lr = (lane >> 4) * 4, lc = lane & 15;
  #pragma unroll
  for (int m = 0; m < 4; ++m) {
    #pragma unroll
    for (int n = 0; n < 4; ++n) {
      const int c = jt * 128 + wcol + n * 16 + lc;
      #pragma unroll
      for (int j = 0; j < 4; ++j) {
        const int r = it * 128 + wrow + m * 16 + lr + j;
        float v = acc[m][n][j];
        if (c > r) v = 0.f;   // strict upper (only on diagonal tiles)
        Sb[(size_t)r * SEQ + c] = f2bf(v);
      }
    }
  }
}

// out = S @ v per batch (K-loop stops at the causal boundary)
__global__ __launch_bounds__(256, 4)
void pv_gemm_kernel(const u16* __restrict__ S, const u16* __restrict__ vT,
                    float* __restrict__ out) {
  extern __shared__ char smem[];      // 32768
  f32x4 acc[4][4];
  const int b = blockIdx.z, it = blockIdx.y, nt = blockIdx.x;
  const u16* Ab = S + (size_t)b * SEQ * SEQ + (size_t)it * 128 * SEQ;
  const u16* Bb = vT + (size_t)b * DIM * SEQ + (size_t)nt * 128 * SEQ;
  gemm128_core(Ab, SEQ, Bb, SEQ, (it + 1) * 4, smem, smem + 16384, acc);

  float* Ob = out + (size_t)b * SEQ * DIM;
  const int tid = threadIdx.x, wid = tid >> 6, lane = tid & 63;
  const int wrow = (wid >> 1) * 64, wcol = (wid & 1) * 64;
  const int lr = (lane >> 4) * 4, lc = lane & 15;
  #pragma unroll
  for (int m = 0; m < 4; ++m) {
    #pragma unroll
    for (int n = 0; n < 4; ++n) {
      const int c = nt * 128 + wcol + n * 16 + lc;
      #pragma unroll
      for (int j = 0; j < 4; ++j) {
        const int r = it * 128 + wrow + m * 16 + lr + j;
        Ob[(size_t)r * DIM + c] = acc[m][n][j];
      }
    }
  }
}

extern "C" void kernel_launch(void* const* d_in, const int* in_sizes, int n_in,
                              void* d_out, int out_size, void* d_ws, size_t ws_size,
                              hipStream_t stream) {
  const float* x    = (const float*)d_in[0];
  const float* W    = (const float*)d_in[1];
  const float* bias = (const float*)d_in[2];
  float* out = (float*)d_out;

  char* ws = (char*)d_ws;
  const size_t SZ_QKV = (size_t)BATCH * SEQ * NQKV * 2;  // 150,994,944
  const size_t SZ_WT  = (size_t)NQKV * DIM * 2;          //   3,538,944
  const size_t SZ_VT  = (size_t)BATCH * DIM * SEQ * 2;   //  50,331,648
  const size_t SZ_S   = (size_t)BATCH * SEQ * SEQ * 2;   //  67,108,864
  const size_t SZ_XB  = (size_t)BATCH * SEQ * DIM * 2;   //  50,331,648
  u16* qkv = (u16*)(ws);
  u16* Wt  = (u16*)(ws + SZ_QKV);
  u16* vT  = (u16*)(ws + SZ_QKV + SZ_WT);
  u16* Smt = (u16*)(ws + SZ_QKV + SZ_WT + SZ_VT);
  u16* Xb  = (u16*)(ws + SZ_QKV + SZ_WT + SZ_VT + SZ_S);
  if (ws_size < SZ_QKV + SZ_WT + SZ_VT + SZ_S + SZ_XB) return;  // need ~322MB

  (void)hipFuncSetAttribute((const void*)qkv_gemm_kernel,
                            hipFuncAttributeMaxDynamicSharedMemorySize, 32768);
  (void)hipFuncSetAttribute((const void*)qk_gemm_kernel,
                            hipFuncAttributeMaxDynamicSharedMemorySize, 32768);
  (void)hipFuncSetAttribute((const void*)pv_gemm_kernel,
                            hipFuncAttributeMaxDynamicSharedMemorySize, 32768);

  cvt_x_kernel<<<dim3((BATCH * SEQ * DIM / 8) / 256), 256, 0, stream>>>(x, Xb);
  wt_kernel<<<dim3(NQKV / 32, DIM / 32), dim3(32, 8), 0, stream>>>(W, Wt);
  qkv_gemm_kernel<<<dim3(4608), 256, 32768, stream>>>(Xb, Wt, bias, qkv, vT);
  qk_gemm_kernel<<<dim3(36, BATCH), 256, 32768, stream>>>(qkv, Smt);
  pv_gemm_kernel<<<dim3(DIM / 128, SEQ / 128, BATCH), 256, 32768, stream>>>(Smt, vT, out);
}

// Round 7
// 283.353 us; speedup vs baseline: 1.2788x; 1.2788x over previous
//
#include <hip/hip_runtime.h>
#include <stdint.h>

#define BATCH 32
#define SEQ   1024
#define DIM   768
#define NQKV  2304   // 3*DIM

typedef unsigned short u16;
typedef __attribute__((ext_vector_type(8))) short short8;   // 8 x bf16 (4 VGPRs)
typedef __attribute__((ext_vector_type(4))) float f32x4;
typedef __attribute__((ext_vector_type(4))) unsigned short us4;

// fp32 -> bf16 round-to-nearest-even (finite inputs)
static __device__ __forceinline__ u16 f2bf(float f) {
  uint32_t u = __float_as_uint(f);
  uint32_t r = (u + 0x7fffu + ((u >> 16) & 1u)) >> 16;
  return (u16)r;
}

static __device__ __forceinline__ void gload_lds16(const void* g, void* l) {
  __builtin_amdgcn_global_load_lds(
      (const __attribute__((address_space(1))) unsigned int*)g,
      (__attribute__((address_space(3))) unsigned int*)l, 16, 0, 0);
}

#define CFENCE asm volatile("" ::: "memory")
static __device__ __forceinline__ void barrier_raw() {
  CFENCE; __builtin_amdgcn_s_barrier(); CFENCE;
}

// ===========================================================================
// 128x128 bt-GEMM core (qkv): ring-2 LDS, 32KB -> ~4 blocks/CU, 4 waves,
// BK=32. Stage T+1 first, then frags, MFMA, __syncthreads (round-6 core —
// best measured qkv config).
// ===========================================================================
static __device__ __forceinline__ void gemm128_core(
    const u16* __restrict__ Ab, int lda,
    const u16* __restrict__ Bb, int ldb,
    int KT, char* smemA, char* smemB, f32x4 (&acc)[4][4])
{
  const int tid  = threadIdx.x;
  const int wid  = tid >> 6;
  const int lane = tid & 63;
  const int wrow = (wid >> 1) * 64;
  const int wcol = (wid & 1) * 64;

  #pragma unroll
  for (int m = 0; m < 4; ++m)
    #pragma unroll
    for (int n = 0; n < 4; ++n)
      acc[m][n] = (f32x4){0.f, 0.f, 0.f, 0.f};

  auto stage = [&](const u16* gb, int ld, char* base, int buf, int half, int kt) {
    const int doff = tid << 4;                          // 0..4095
    const int loff = doff ^ (((doff >> 7) & 3) << 4);   // involution
    const int row  = half * 64 + (loff >> 6);           // 0..127
    const int colb = loff & 63;
    const char* src = (const char*)gb + ((size_t)row * ld + (size_t)kt * 32) * 2 + colb;
    char* dst = base + buf * 8192 + half * 4096 + (wid << 10);  // wave-uniform
    gload_lds16(src, dst);
  };
  auto stage_tile = [&](int kt, int buf) {
    stage(Ab, lda, smemA, buf, 0, kt); stage(Ab, lda, smemA, buf, 1, kt);
    stage(Bb, ldb, smemB, buf, 0, kt); stage(Bb, ldb, smemB, buf, 1, kt);
  };

  const int lrow = lane & 15;
  const int c0   = lane >> 4;

  stage_tile(0, 0);
  __syncthreads();

  for (int T = 0; T < KT; ++T) {
    const int buf = T & 1;
    if (T + 1 < KT) stage_tile(T + 1, buf ^ 1);   // issue early: hidden by MFMAs
    const char* ab = smemA + buf * 8192;
    const char* bb = smemB + buf * 8192;
    short8 af[4], bf[4];
    #pragma unroll
    for (int n = 0; n < 4; ++n) {
      const int row = wcol + n * 16 + lrow;
      const int c = c0 ^ ((row >> 1) & 3);
      bf[n] = *(const short8*)(bb + row * 64 + c * 16);
    }
    #pragma unroll
    for (int m = 0; m < 4; ++m) {
      const int row = wrow + m * 16 + lrow;
      const int c = c0 ^ ((row >> 1) & 3);
      af[m] = *(const short8*)(ab + row * 64 + c * 16);
    }
    __builtin_amdgcn_s_setprio(1);
    #pragma unroll
    for (int m = 0; m < 4; ++m)
      #pragma unroll
      for (int n = 0; n < 4; ++n)
        acc[m][n] = __builtin_amdgcn_mfma_f32_16x16x32_bf16(af[m], bf[n], acc[m][n], 0, 0, 0);
    __builtin_amdgcn_s_setprio(0);
    __syncthreads();
  }
}

// ===========================================================================
// 128x128 ring-of-4 counted-vmcnt core (round-5 version): 64KB LDS ->
// 2 blocks/CU, 1 counted vmcnt + fine phases per K-tile. Used by qk / pv
// (proven faster for these than the syncthreads-drain core).
// ===========================================================================
static __device__ __forceinline__ void ring_core_128(
    const u16* __restrict__ Ab, int lda,
    const u16* __restrict__ Bb, int ldb,
    int KT, char* smemA, char* smemB, f32x4 (&acc)[4][4])
{
  const int tid  = threadIdx.x;
  const int wid  = tid >> 6;
  const int lane = tid & 63;
  const int wrow = (wid >> 1) * 64;
  const int wcol = (wid & 1) * 64;

  #pragma unroll
  for (int m = 0; m < 4; ++m)
    #pragma unroll
    for (int n = 0; n < 4; ++n)
      acc[m][n] = (f32x4){0.f, 0.f, 0.f, 0.f};

  auto stage = [&](const u16* gb, int ld, char* lsbase, int ring, int half, int kt) {
    const int doff = tid << 4;                          // 0..4095
    const int loff = doff ^ (((doff >> 7) & 3) << 4);   // involution on bits 4-5
    const int row  = half * 64 + (loff >> 6);           // 0..127
    const int colb = loff & 63;
    const char* src = (const char*)gb + ((size_t)row * ld + (size_t)kt * 32) * 2 + colb;
    char* dst = lsbase + ring * 8192 + half * 4096 + (wid << 10);  // wave-uniform
    gload_lds16(src, dst);
  };

  // prologue: stage tiles 0,1,2 (callers guarantee KT >= 4)
  for (int t = 0; t < 3; ++t) {
    stage(Ab, lda, smemA, t, 0, t); stage(Ab, lda, smemA, t, 1, t);
    stage(Bb, ldb, smemB, t, 0, t); stage(Bb, ldb, smemB, t, 1, t);
  }
  asm volatile("s_waitcnt vmcnt(8)" ::: "memory");
  barrier_raw();

  const int lrow = lane & 15;
  const int c0   = lane >> 4;

  for (int T = 0; T < KT; ++T) {
    const int ring = T & 3;
    const char* abase = smemA + ring * 8192;
    const char* bbase = smemB + ring * 8192;
    const int r3 = (T + 3) & 3;
    short8 af[2], bf[4];

    // ---- phase 1: B n0-3 + A m0-1; stage A halves of T+3 ----
    #pragma unroll
    for (int n = 0; n < 4; ++n) {
      const int row = wcol + n * 16 + lrow;
      const int c = c0 ^ ((row >> 1) & 3);
      bf[n] = *(const short8*)(bbase + row * 64 + c * 16);
    }
    #pragma unroll
    for (int m = 0; m < 2; ++m) {
      const int row = wrow + m * 16 + lrow;
      const int c = c0 ^ ((row >> 1) & 3);
      af[m] = *(const short8*)(abase + row * 64 + c * 16);
    }
    if (T + 3 < KT) {
      stage(Ab, lda, smemA, r3, 0, T + 3); stage(Ab, lda, smemA, r3, 1, T + 3);
    }
    barrier_raw();
    asm volatile("s_waitcnt lgkmcnt(0)" ::: "memory");
    __builtin_amdgcn_sched_barrier(0);
    __builtin_amdgcn_s_setprio(1);
    #pragma unroll
    for (int m = 0; m < 2; ++m)
      #pragma unroll
      for (int n = 0; n < 4; ++n)
        acc[m][n] = __builtin_amdgcn_mfma_f32_16x16x32_bf16(af[m], bf[n], acc[m][n], 0, 0, 0);
    __builtin_amdgcn_s_setprio(0);
    barrier_raw();

    // ---- phase 2: A m2-3; stage B halves of T+3 ----
    #pragma unroll
    for (int m = 0; m < 2; ++m) {
      const int row = wrow + (m + 2) * 16 + lrow;
      const int c = c0 ^ ((row >> 1) & 3);
      af[m] = *(const short8*)(abase + row * 64 + c * 16);
    }
    if (T + 3 < KT) {
      stage(Bb, ldb, smemB, r3, 0, T + 3); stage(Bb, ldb, smemB, r3, 1, T + 3);
    }
    barrier_raw();
    asm volatile("s_waitcnt lgkmcnt(0)" ::: "memory");
    __builtin_amdgcn_sched_barrier(0);
    __builtin_amdgcn_s_setprio(1);
    #pragma unroll
    for (int m = 0; m < 2; ++m)
      #pragma unroll
      for (int n = 0; n < 4; ++n)
        acc[m + 2][n] = __builtin_amdgcn_mfma_f32_16x16x32_bf16(af[m], bf[n], acc[m + 2][n], 0, 0, 0);
    __builtin_amdgcn_s_setprio(0);
    if (T + 1 < KT) {
      if (T + 3 < KT)      { asm volatile("s_waitcnt vmcnt(8)" ::: "memory"); }
      else if (T + 2 < KT) { asm volatile("s_waitcnt vmcnt(4)" ::: "memory"); }
      else                 { asm volatile("s_waitcnt vmcnt(0)" ::: "memory"); }
      barrier_raw();
    }
  }
}

// ===========================================================================
// qkv = x @ W + b with decay folded; v written transposed to vT directly.
// ===========================================================================
__global__ __launch_bounds__(256, 4)
void qkv_gemm_kernel(const u16* __restrict__ Xb, const u16* __restrict__ Wt,
                     const float* __restrict__ bias, u16* __restrict__ qkv,
                     u16* __restrict__ vT) {
  extern __shared__ char smem[];     // 32768
  f32x4 acc[4][4];

  const int bid = blockIdx.x;                      // 4608 blocks, %8==0
  const int swz = (bid & 7) * 576 + (bid >> 3);    // bijective XCD swizzle
  const int mt = swz / 18;                         // 0..255
  const int nt = swz % 18;                         // 0..17

  gemm128_core(Xb + (size_t)mt * 128 * DIM, DIM,
               Wt + (size_t)nt * 128 * DIM, DIM, DIM / 32,
               smem, smem + 16384, acc);

  const int tid = threadIdx.x, wid = tid >> 6, lane = tid & 63;
  const int wrow = (wid >> 1) * 64, wcol = (wid & 1) * 64;
  const int lr = (lane >> 4) * 4, lc = lane & 15;
  const float L2A = -0.014499570f;     // log2(0.99)
  const float ISD = 0.03608439182f;    // 1/sqrt(768)
  const int seg = nt / 6;              // uniform per block
  float bv[4];
  #pragma unroll
  for (int n = 0; n < 4; ++n)
    bv[n] = bias[nt * 128 + wcol + n * 16 + lc];

  if (seg < 2) {
    #pragma unroll
    for (int m = 0; m < 4; ++m) {
      const int grow0 = mt * 128 + wrow + m * 16 + lr;
      #pragma unroll
      for (int j = 0; j < 4; ++j) {
        const int s = (grow0 + j) & (SEQ - 1);
        const float scale = (seg == 0) ? exp2f((float)s * L2A) * ISD
                                       : exp2f(-(float)s * L2A);
        #pragma unroll
        for (int n = 0; n < 4; ++n) {
          const int gcol = nt * 128 + wcol + n * 16 + lc;
          qkv[(size_t)(grow0 + j) * NQKV + gcol] = f2bf((acc[m][n][j] + bv[n]) * scale);
        }
      }
    }
  } else {
    #pragma unroll
    for (int m = 0; m < 4; ++m) {
      const int grow0 = mt * 128 + wrow + m * 16 + lr;
      const int b  = grow0 >> 10;
      const int t0 = grow0 & (SEQ - 1);
      #pragma unroll
      for (int n = 0; n < 4; ++n) {
        const int d = (nt - 12) * 128 + wcol + n * 16 + lc;
        us4 val;
        #pragma unroll
        for (int j = 0; j < 4; ++j) val[j] = f2bf(acc[m][n][j] + bv[n]);
        *(us4*)(vT + ((size_t)b * DIM + d) * SEQ + t0) = val;
      }
    }
  }
}

// ---------------------------------------------------------------------------
// x fp32 -> bf16
__global__ __launch_bounds__(256)
void cvt_x_kernel(const float* __restrict__ X, u16* __restrict__ Xb) {
  const size_t i = ((size_t)blockIdx.x * 256 + threadIdx.x) * 8;
  f32x4 a = *(const f32x4*)(X + i);
  f32x4 b = *(const f32x4*)(X + i + 4);
  short8 r;
  #pragma unroll
  for (int j = 0; j < 4; ++j) { r[j] = (short)f2bf(a[j]); r[j + 4] = (short)f2bf(b[j]); }
  *(short8*)(Xb + i) = r;
}

// W [768][2304] fp32 -> Wt [2304][768] bf16
__global__ void wt_kernel(const float* __restrict__ W, u16* __restrict__ Wt) {
  __shared__ u16 t[32][33];
  const int n0 = blockIdx.x * 32, k0 = blockIdx.y * 32;
  const int tx = threadIdx.x, ty = threadIdx.y;
  #pragma unroll
  for (int r = 0; r < 4; ++r)
    t[ty + r * 8][tx] = f2bf(W[(size_t)(k0 + ty + r * 8) * NQKV + n0 + tx]);
  __syncthreads();
  #pragma unroll
  for (int r = 0; r < 4; ++r)
    Wt[(size_t)(n0 + ty + r * 8) * DIM + k0 + tx] = t[tx][ty + r * 8];
}

// S = q~ @ k~^T per batch, lower-triangular tiles only; strict-upper zeroed.
// Grid flattened 1152 with XCD grouping: 4 whole batches per XCD chunk.
__global__ __launch_bounds__(256, 2)
void qk_gemm_kernel(const u16* __restrict__ qkv, u16* __restrict__ S) {
  extern __shared__ char smem[];      // 65536
  f32x4 acc[4][4];
  const int bid = blockIdx.x;                      // 1152 = 8 * 144
  const int swz = (bid & 7) * 144 + (bid >> 3);    // bijective
  const int b = swz / 36;
  const int p = swz % 36;             // triangular pair
  int it = 0;
  while ((it + 1) * (it + 2) / 2 <= p) ++it;
  const int jt = p - it * (it + 1) / 2;
  const u16* Ab = qkv + (size_t)(b * SEQ + it * 128) * NQKV;        // q rows
  const u16* Bb = qkv + (size_t)(b * SEQ + jt * 128) * NQKV + DIM;  // k rows
  ring_core_128(Ab, NQKV, Bb, NQKV, DIM / 32, smem, smem + 32768, acc);

  u16* Sb = S + (size_t)b * SEQ * SEQ;
  const int tid = threadIdx.x, wid = tid >> 6, lane = tid & 63;
  const int wrow = (wid >> 1) * 64, wcol = (wid & 1) * 64;
  const int lr = (lane >> 4) * 4, lc = lane & 15;
  #pragma unroll
  for (int m = 0; m < 4; ++m) {
    #pragma unroll
    for (int n = 0; n < 4; ++n) {
      const int c = jt * 128 + wcol + n * 16 + lc;
      #pragma unroll
      for (int j = 0; j < 4; ++j) {
        const int r = it * 128 + wrow + m * 16 + lr + j;
        float v = acc[m][n][j];
        if (c > r) v = 0.f;   // strict upper (only on diagonal tiles)
        Sb[(size_t)r * SEQ + c] = f2bf(v);
      }
    }
  }
}

// out = S @ v per batch (K-loop stops at the causal boundary).
// Grid flattened 1536 with XCD grouping: the 6 nt-siblings of one (b,it)
// (sharing the same S rows) stay on one XCD.
__global__ __launch_bounds__(256, 2)
void pv_gemm_kernel(const u16* __restrict__ S, const u16* __restrict__ vT,
                    float* __restrict__ out) {
  extern __shared__ char smem[];      // 65536
  f32x4 acc[4][4];
  const int bid = blockIdx.x;                      // 1536 = 8 * 192
  const int swz = (bid & 7) * 192 + (bid >> 3);    // bijective
  const int b   = swz / 48;
  const int rem = swz % 48;
  const int it  = rem / 6;
  const int nt  = rem % 6;
  const u16* Ab = S + (size_t)b * SEQ * SEQ + (size_t)it * 128 * SEQ;
  const u16* Bb = vT + (size_t)b * DIM * SEQ + (size_t)nt * 128 * SEQ;
  ring_core_128(Ab, SEQ, Bb, SEQ, (it + 1) * 4, smem, smem + 32768, acc);

  float* Ob = out + (size_t)b * SEQ * DIM;
  const int tid = threadIdx.x, wid = tid >> 6, lane = tid & 63;
  const int wrow = (wid >> 1) * 64, wcol = (wid & 1) * 64;
  const int lr = (lane >> 4) * 4, lc = lane & 15;
  #pragma unroll
  for (int m = 0; m < 4; ++m) {
    #pragma unroll
    for (int n = 0; n < 4; ++n) {
      const int c = nt * 128 + wcol + n * 16 + lc;
      #pragma unroll
      for (int j = 0; j < 4; ++j) {
        const int r = it * 128 + wrow + m * 16 + lr + j;
        Ob[(size_t)r * DIM + c] = acc[m][n][j];
      }
    }
  }
}

extern "C" void kernel_launch(void* const* d_in, const int* in_sizes, int n_in,
                              void* d_out, int out_size, void* d_ws, size_t ws_size,
                              hipStream_t stream) {
  const float* x    = (const float*)d_in[0];
  const float* W    = (const float*)d_in[1];
  const float* bias = (const float*)d_in[2];
  float* out = (float*)d_out;

  char* ws = (char*)d_ws;
  const size_t SZ_QKV = (size_t)BATCH * SEQ * NQKV * 2;  // 150,994,944
  const size_t SZ_WT  = (size_t)NQKV * DIM * 2;          //   3,538,944
  const size_t SZ_VT  = (size_t)BATCH * DIM * SEQ * 2;   //  50,331,648
  const size_t SZ_S   = (size_t)BATCH * SEQ * SEQ * 2;   //  67,108,864
  const size_t SZ_XB  = (size_t)BATCH * SEQ * DIM * 2;   //  50,331,648
  u16* qkv = (u16*)(ws);
  u16* Wt  = (u16*)(ws + SZ_QKV);
  u16* vT  = (u16*)(ws + SZ_QKV + SZ_WT);
  u16* Smt = (u16*)(ws + SZ_QKV + SZ_WT + SZ_VT);
  u16* Xb  = (u16*)(ws + SZ_QKV + SZ_WT + SZ_VT + SZ_S);
  if (ws_size < SZ_QKV + SZ_WT + SZ_VT + SZ_S + SZ_XB) return;  // need ~322MB

  (void)hipFuncSetAttribute((const void*)qkv_gemm_kernel,
                            hipFuncAttributeMaxDynamicSharedMemorySize, 32768);
  (void)hipFuncSetAttribute((const void*)qk_gemm_kernel,
                            hipFuncAttributeMaxDynamicSharedMemorySize, 65536);
  (void)hipFuncSetAttribute((const void*)pv_gemm_kernel,
                            hipFuncAttributeMaxDynamicSharedMemorySize, 65536);

  cvt_x_kernel<<<dim3((BATCH * SEQ * DIM / 8) / 256), 256, 0, stream>>>(x, Xb);
  wt_kernel<<<dim3(NQKV / 32, DIM / 32), dim3(32, 8), 0, stream>>>(W, Wt);
  qkv_gemm_kernel<<<dim3(4608), 256, 32768, stream>>>(Xb, Wt, bias, qkv, vT);
  qk_gemm_kernel<<<dim3(1152), 256, 65536, stream>>>(qkv, Smt);
  pv_gemm_kernel<<<dim3(1536), 256, 65536, stream>>>(Smt, vT, out);
}